// Round 4
// baseline (389.515 us; speedup 1.0000x reference)
//
#include <hip/hip_runtime.h>

#define H 10
#define T_LEN 2048
#define BATCH 8192

// row_ror:K within each 16-lane row: dst lane i reads src lane (i-K)&15.
// (Direction verified on hardware in an earlier passing version.)
// __builtin_amdgcn_mov_dpp has NO 'old' operand -> no zero-mov tax.
#define MOVROR(x, K) __int_as_float(__builtin_amdgcn_mov_dpp(                    \
    __float_as_int(x), 0x120 + (K), 0xF, 0xF, true))

// ---------------------------------------------------------------------------
// Kernel 1: Bmat = expm(triu(A,1) - triu(A,1)^T) in fp64, write fp32 to ws.
// ---------------------------------------------------------------------------
__global__ void expm_kernel(const float* __restrict__ A, float* __restrict__ Bout) {
    __shared__ double S[H][H];
    __shared__ double P[H][H];
    __shared__ double E[H][H];
    const int tid = threadIdx.x;
    const int i = tid / H, j = tid % H;
    if (tid < H * H) {
        double a = 0.0;
        if (i < j) a = (double)A[i * H + j];
        else if (i > j) a = -(double)A[j * H + i];
        a *= (1.0 / 256.0);          // scale by 2^-8
        S[i][j] = a;
        P[i][j] = a;                 // S^1 / 1!
        E[i][j] = (i == j ? 1.0 : 0.0) + a;
    }
    __syncthreads();
    for (int k = 2; k <= 16; ++k) {
        double acc = 0.0;
        if (tid < H * H) {
            for (int m = 0; m < H; ++m) acc += P[i][m] * S[m][j];
            acc *= (1.0 / (double)k);
        }
        __syncthreads();
        if (tid < H * H) { P[i][j] = acc; E[i][j] += acc; }
        __syncthreads();
    }
    for (int rr = 0; rr < 8; ++rr) {
        double acc = 0.0;
        if (tid < H * H) {
            for (int m = 0; m < H; ++m) acc += E[i][m] * E[m][j];
        }
        __syncthreads();
        if (tid < H * H) E[i][j] = acc;
        __syncthreads();
    }
    if (tid < H * H) Bout[i * H + j] = (float)E[i][j];
}

// ---------------------------------------------------------------------------
// Kernel 2: 16 lanes per batch element, one h component per lane (H 10->16,
// pads provably stay 0: zero B cols, zero W rows, zero bias => modrelu(0)=0).
// 4 batches/wave, grid 2048 blocks => 2 waves/SIMD: the second wave hides the
// first wave's dependent-chain stalls (round-3 showed 30% stall at 1 wave).
// Per step: 15 v_mov_dpp + 16 v_fmac + 2 xproj + 3 modrelu ~= 37 instr.
// ---------------------------------------------------------------------------
__global__ __launch_bounds__(64)
void rnn_kernel(const float* __restrict__ x,
                const float* __restrict__ Bm,
                const float* __restrict__ Win,
                const float* __restrict__ bmod,
                const float* __restrict__ lW,
                const float* __restrict__ lb,
                float* __restrict__ out) {
    const int lane = threadIdx.x;
    const int j    = lane & 15;          // owned h component
    const int row  = lane >> 4;          // 0..3: batch within wave
    const int bb   = blockIdx.x * 4 + row;   // 8192 = 2048*4 exact

    // Rotation k delivers h[(j-k)&15]; Brot[k] = B[(j-k)&15][j] (0 on pads).
    float Brot[16];
#pragma unroll
    for (int k = 0; k < 16; ++k) {
        const int m = (j - k) & 15;
        Brot[k] = (j < H && m < H) ? Bm[m * H + j] : 0.f;
    }
    float w0j = 0.f, w1j = 0.f, bmj = 0.f;
    if (j < H) { w0j = Win[j * 2]; w1j = Win[j * 2 + 1]; bmj = bmod[j]; }

    float h = 0.f;

    // All 16 lanes of a group read the same x stream (L1-broadcast; HBM at 4%).
    const float4* __restrict__ xp4 = (const float4*)(x + (size_t)bb * (T_LEN * 2));
    float4 buf[8];
#pragma unroll
    for (int i = 0; i < 8; ++i) buf[i] = xp4[i];

    for (int t0 = 0; t0 < T_LEN; t0 += 16) {
        float4 c[8];
#pragma unroll
        for (int i = 0; i < 8; ++i) c[i] = buf[i];
        if (t0 + 16 < T_LEN) {
            const int base = (t0 + 16) >> 1;
#pragma unroll
            for (int i = 0; i < 8; ++i) buf[i] = xp4[base + i];
        }

#pragma unroll
        for (int u = 0; u < 16; ++u) {
            const int ii = u >> 1;
            const float x0 = (u & 1) ? c[ii].z : c[ii].x;
            const float x1 = (u & 1) ? c[ii].w : c[ii].y;

            float acc = fmaf(x1, w1j, x0 * w0j);
            acc = fmaf(h, Brot[0], acc);
#define STEPK(K) { const float e_ = MOVROR(h, K); acc = fmaf(e_, Brot[K], acc); }
            STEPK(1)  STEPK(2)  STEPK(3)  STEPK(4)  STEPK(5)
            STEPK(6)  STEPK(7)  STEPK(8)  STEPK(9)  STEPK(10)
            STEPK(11) STEPK(12) STEPK(13) STEPK(14) STEPK(15)
#undef STEPK
            const float s = acc;
            const float r = fmaxf(fabsf(s) + bmj, 0.f);
            h = __builtin_copysignf(r, s);
        }
    }

    // epilogue: out[bb][j] = lb[j] + sum_m h[m] * lW[j][m], same rotation gather
    float Lrot[16];
#pragma unroll
    for (int k = 0; k < 16; ++k) {
        const int m = (j - k) & 15;
        Lrot[k] = (j < H && m < H) ? lW[j * H + m] : 0.f;
    }
    float acc = (j < H) ? lb[j] : 0.f;
    acc = fmaf(h, Lrot[0], acc);
#define OUTK(K) { const float e_ = MOVROR(h, K); acc = fmaf(e_, Lrot[K], acc); }
    OUTK(1)  OUTK(2)  OUTK(3)  OUTK(4)  OUTK(5)
    OUTK(6)  OUTK(7)  OUTK(8)  OUTK(9)  OUTK(10)
    OUTK(11) OUTK(12) OUTK(13) OUTK(14) OUTK(15)
#undef OUTK
    if (j < H) out[(size_t)bb * H + j] = acc;
}

extern "C" void kernel_launch(void* const* d_in, const int* in_sizes, int n_in,
                              void* d_out, int out_size, void* d_ws, size_t ws_size,
                              hipStream_t stream) {
    const float* inputs = (const float*)d_in[0];  // [8192, 2048, 2]
    const float* A      = (const float*)d_in[1];  // [10, 10]
    const float* W_in   = (const float*)d_in[2];  // [10, 2]
    const float* b_mod  = (const float*)d_in[3];  // [10]
    const float* lin_W  = (const float*)d_in[4];  // [10, 10]
    const float* lin_b  = (const float*)d_in[5];  // [10]
    float* out = (float*)d_out;                   // [8192, 10]
    float* Bmat = (float*)d_ws;                   // 100 floats scratch

    expm_kernel<<<1, 128, 0, stream>>>(A, Bmat);
    rnn_kernel<<<BATCH / 4, 64, 0, stream>>>(inputs, Bmat, W_in, b_mod,
                                             lin_W, lin_b, out);
}

// Round 5
// 345.411 us; speedup vs baseline: 1.1277x; 1.1277x over previous
//
#include <hip/hip_runtime.h>

#define H 10
#define T_LEN 2048
#define BATCH 8192

// row_ror:K within each 16-lane row: dst lane i reads src lane (i-K)&15.
// (Direction verified on hardware: rounds 1/3/4 all passed with this mapping.)
#define MOVROR(x, K) __int_as_float(__builtin_amdgcn_mov_dpp(                    \
    __float_as_int(x), 0x120 + (K), 0xF, 0xF, true))

// Fused rotate+FMA: v_fmac_f32 is VOP2 -> DPP-legal. One instruction replaces
// {v_mov_b32_dpp + v_fma_f32}. acc is the tied dst (normal interlocked read);
// hh is the DPP-rotated source.
#define STR_(x) #x
#define FMAC_ROR(acc, hh, bk, K)                                                  \
    asm("v_fmac_f32 %0, %1, %2 row_ror:" STR_(K) " row_mask:0xf bank_mask:0xf"    \
        : "+v"(acc) : "v"(hh), "v"(bk))
// First DPP read of h after its VALU write needs 2 wait states (DPP-source
// hazard is not HW-interlocked); bake the s_nop into the same asm so no
// scheduler reordering can separate them.
#define FMAC_ROR1(acc, hh, bk)                                                    \
    asm("s_nop 1\n\tv_fmac_f32 %0, %1, %2 row_ror:1 row_mask:0xf bank_mask:0xf"   \
        : "+v"(acc) : "v"(hh), "v"(bk))

// ---------------------------------------------------------------------------
// Kernel 1: Bmat = expm(triu(A,1) - triu(A,1)^T) in fp64, write fp32 to ws.
// ---------------------------------------------------------------------------
__global__ void expm_kernel(const float* __restrict__ A, float* __restrict__ Bout) {
    __shared__ double S[H][H];
    __shared__ double P[H][H];
    __shared__ double E[H][H];
    const int tid = threadIdx.x;
    const int i = tid / H, j = tid % H;
    if (tid < H * H) {
        double a = 0.0;
        if (i < j) a = (double)A[i * H + j];
        else if (i > j) a = -(double)A[j * H + i];
        a *= (1.0 / 256.0);          // scale by 2^-8
        S[i][j] = a;
        P[i][j] = a;                 // S^1 / 1!
        E[i][j] = (i == j ? 1.0 : 0.0) + a;
    }
    __syncthreads();
    for (int k = 2; k <= 16; ++k) {
        double acc = 0.0;
        if (tid < H * H) {
            for (int m = 0; m < H; ++m) acc += P[i][m] * S[m][j];
            acc *= (1.0 / (double)k);
        }
        __syncthreads();
        if (tid < H * H) { P[i][j] = acc; E[i][j] += acc; }
        __syncthreads();
    }
    for (int rr = 0; rr < 8; ++rr) {
        double acc = 0.0;
        if (tid < H * H) {
            for (int m = 0; m < H; ++m) acc += E[i][m] * E[m][j];
        }
        __syncthreads();
        if (tid < H * H) E[i][j] = acc;
        __syncthreads();
    }
    if (tid < H * H) Bout[i * H + j] = (float)E[i][j];
}

// ---------------------------------------------------------------------------
// Kernel 2: 16 lanes per batch element, one h component per lane (H 10->16,
// pads provably stay 0). 4 batches/wave, 2048 waves => 2 waves/SIMD.
// Per step: 1 v_mul + 1 v_fma (xproj) + 16 v_fmac_f32 (15 with fused DPP
// row_ror) + 3-op modrelu ~= 21 VALU. __launch_bounds__(64,2) raises the
// VGPR budget to 256 so both x double-buffers live in registers (round-4's
// 56-VGPR squeeze rewrote the prefetch into ~2x the instructions).
// ---------------------------------------------------------------------------
struct RnnConsts {
    float w0j, w1j, bmj;
};

__device__ __forceinline__ void rnn_step(float x0, float x1, float& h,
                                         const float (&Brot)[16],
                                         const RnnConsts& cst) {
    float acc = fmaf(x1, cst.w1j, x0 * cst.w0j);
    acc = fmaf(h, Brot[0], acc);         // plain fmac, k=0 (also spaces hazard)
    FMAC_ROR1(acc, h, Brot[1]);
    FMAC_ROR(acc, h, Brot[2],  2);
    FMAC_ROR(acc, h, Brot[3],  3);
    FMAC_ROR(acc, h, Brot[4],  4);
    FMAC_ROR(acc, h, Brot[5],  5);
    FMAC_ROR(acc, h, Brot[6],  6);
    FMAC_ROR(acc, h, Brot[7],  7);
    FMAC_ROR(acc, h, Brot[8],  8);
    FMAC_ROR(acc, h, Brot[9],  9);
    FMAC_ROR(acc, h, Brot[10], 10);
    FMAC_ROR(acc, h, Brot[11], 11);
    FMAC_ROR(acc, h, Brot[12], 12);
    FMAC_ROR(acc, h, Brot[13], 13);
    FMAC_ROR(acc, h, Brot[14], 14);
    FMAC_ROR(acc, h, Brot[15], 15);
    const float r = fmaxf(fabsf(acc) + cst.bmj, 0.f);
    h = __builtin_copysignf(r, acc);
}

__device__ __forceinline__ void run16(const float4 (&c)[8], float& h,
                                      const float (&Brot)[16],
                                      const RnnConsts& cst) {
#pragma unroll
    for (int u = 0; u < 16; ++u) {
        const int ii = u >> 1;
        const float x0 = (u & 1) ? c[ii].z : c[ii].x;
        const float x1 = (u & 1) ? c[ii].w : c[ii].y;
        rnn_step(x0, x1, h, Brot, cst);
    }
}

__global__ __launch_bounds__(64, 2)
void rnn_kernel(const float* __restrict__ x,
                const float* __restrict__ Bm,
                const float* __restrict__ Win,
                const float* __restrict__ bmod,
                const float* __restrict__ lW,
                const float* __restrict__ lb,
                float* __restrict__ out) {
    const int lane = threadIdx.x;
    const int j    = lane & 15;          // owned h component
    const int row  = lane >> 4;          // 0..3: batch within wave
    const int bb   = blockIdx.x * 4 + row;   // 8192 = 2048*4 exact

    // Rotation k delivers h[(j-k)&15]; Brot[k] = B[(j-k)&15][j] (0 on pads).
    float Brot[16];
#pragma unroll
    for (int k = 0; k < 16; ++k) {
        const int m = (j - k) & 15;
        Brot[k] = (j < H && m < H) ? Bm[m * H + j] : 0.f;
    }
    RnnConsts cst = {0.f, 0.f, 0.f};
    if (j < H) { cst.w0j = Win[j * 2]; cst.w1j = Win[j * 2 + 1]; cst.bmj = bmod[j]; }

    float h = 0.f;

    const float4* __restrict__ xp4 = (const float4*)(x + (size_t)bb * (T_LEN * 2));
    float4 bA[8], bB[8];
#pragma unroll
    for (int i = 0; i < 8; ++i) bA[i] = xp4[i];

    for (int t0 = 0; t0 < T_LEN; t0 += 32) {
        // prefetch steps t0+16..t0+31 (always in range: t0 <= 2016)
        const int baseB = (t0 + 16) >> 1;
#pragma unroll
        for (int i = 0; i < 8; ++i) bB[i] = xp4[baseB + i];
        run16(bA, h, Brot, cst);
        if (t0 + 32 < T_LEN) {
            const int baseA = (t0 + 32) >> 1;
#pragma unroll
            for (int i = 0; i < 8; ++i) bA[i] = xp4[baseA + i];
        }
        run16(bB, h, Brot, cst);
    }

    // epilogue: out[bb][j] = lb[j] + sum_m h[m] * lW[j][m] (cold; builtin DPP)
    float Lrot[16];
#pragma unroll
    for (int k = 0; k < 16; ++k) {
        const int m = (j - k) & 15;
        Lrot[k] = (j < H && m < H) ? lW[j * H + m] : 0.f;
    }
    float acc = (j < H) ? lb[j] : 0.f;
    acc = fmaf(h, Lrot[0], acc);
#define OUTK(K) { const float e_ = MOVROR(h, K); acc = fmaf(e_, Lrot[K], acc); }
    OUTK(1)  OUTK(2)  OUTK(3)  OUTK(4)  OUTK(5)
    OUTK(6)  OUTK(7)  OUTK(8)  OUTK(9)  OUTK(10)
    OUTK(11) OUTK(12) OUTK(13) OUTK(14) OUTK(15)
#undef OUTK
    if (j < H) out[(size_t)bb * H + j] = acc;
}

extern "C" void kernel_launch(void* const* d_in, const int* in_sizes, int n_in,
                              void* d_out, int out_size, void* d_ws, size_t ws_size,
                              hipStream_t stream) {
    const float* inputs = (const float*)d_in[0];  // [8192, 2048, 2]
    const float* A      = (const float*)d_in[1];  // [10, 10]
    const float* W_in   = (const float*)d_in[2];  // [10, 2]
    const float* b_mod  = (const float*)d_in[3];  // [10]
    const float* lin_W  = (const float*)d_in[4];  // [10, 10]
    const float* lin_b  = (const float*)d_in[5];  // [10]
    float* out = (float*)d_out;                   // [8192, 10]
    float* Bmat = (float*)d_ws;                   // 100 floats scratch

    expm_kernel<<<1, 128, 0, stream>>>(A, Bmat);
    rnn_kernel<<<BATCH / 4, 64, 0, stream>>>(inputs, Bmat, W_in, b_mod,
                                             lin_W, lin_b, out);
}

// Round 6
// 333.924 us; speedup vs baseline: 1.1665x; 1.0344x over previous
//
#include <hip/hip_runtime.h>

#define H 10
#define T_LEN 2048
#define BATCH 8192

// row_ror:K within each 16-lane row: dst lane i reads src lane (i-K)&15.
// Direction + v_fmac DPP fusion verified on hardware (rounds 1,3,4,5 passed).
#define MOVROR(x, K) __int_as_float(__builtin_amdgcn_mov_dpp(                    \
    __float_as_int(x), 0x120 + (K), 0xF, 0xF, true))

#define STR2(x) #x
#define VREG(n) "v" STR2(n)
#define DPP_(K) " row_ror:" STR2(K) " row_mask:0xf bank_mask:0xf\n\t"

// One recurrence step, 23 VALU instrs. v62=chainA, v63=chainB then tmp.
// Chains interleaved so dependent-FMA latency (4cy) hides under issue (2cy).
// h DPP-read is >=3 instrs after its v_bfi write (>=2 wait states required).
#define STEP(X0, X1)                                                \
    "v_mul_f32 v62, " VREG(X0) ", %[w0]\n\t"                        \
    "v_fmac_f32 v62, " VREG(X1) ", %[w1]\n\t"                       \
    "v_fmac_f32 v62, %[h], %[b0]\n\t"                               \
    "v_mul_f32 v63, %[h], %[b8]" DPP_(8)                            \
    "v_fmac_f32 v62, %[h], %[b1]" DPP_(1)                           \
    "v_fmac_f32 v63, %[h], %[b9]" DPP_(9)                           \
    "v_fmac_f32 v62, %[h], %[b2]" DPP_(2)                           \
    "v_fmac_f32 v63, %[h], %[b10]" DPP_(10)                         \
    "v_fmac_f32 v62, %[h], %[b3]" DPP_(3)                           \
    "v_fmac_f32 v63, %[h], %[b11]" DPP_(11)                         \
    "v_fmac_f32 v62, %[h], %[b4]" DPP_(4)                           \
    "v_fmac_f32 v63, %[h], %[b12]" DPP_(12)                         \
    "v_fmac_f32 v62, %[h], %[b5]" DPP_(5)                           \
    "v_fmac_f32 v63, %[h], %[b13]" DPP_(13)                         \
    "v_fmac_f32 v62, %[h], %[b6]" DPP_(6)                           \
    "v_fmac_f32 v63, %[h], %[b14]" DPP_(14)                         \
    "v_fmac_f32 v62, %[h], %[b7]" DPP_(7)                           \
    "v_fmac_f32 v63, %[h], %[b15]" DPP_(15)                         \
    "v_add_f32 v62, v62, v63\n\t"                                   \
    "v_and_b32 v63, %[mk], v62\n\t"                                 \
    "v_add_f32 v63, v63, %[bm]\n\t"                                 \
    "v_max_f32 v63, 0, v63\n\t"                                     \
    "v_bfi_b32 %[h], %[mk], v63, v62\n\t"

// Sub-iter control: issue 4 dwordx4 into the buffer 3 sub-iters ahead,
// counted wait vmcnt(12) (12 newer loads stay in flight). Last 3 sub-iters
// (it>=253) skip issue and drain. LD0..LD3 are the dst-tuple strings.
#define SUBCTL(TAG, LD0, LD1, LD2, LD3)                             \
    "s_cmp_lt_u32 %[it], 253\n\t"                                   \
    "s_cbranch_scc0 Lsk" TAG "_%=\n\t"                              \
    "global_load_dwordx4 " LD0 ", v[60:61], off\n\t"                \
    "global_load_dwordx4 " LD1 ", v[60:61], off offset:16\n\t"      \
    "global_load_dwordx4 " LD2 ", v[60:61], off offset:32\n\t"      \
    "global_load_dwordx4 " LD3 ", v[60:61], off offset:48\n\t"      \
    "v_add_co_u32 v60, vcc, 64, v60\n\t"                            \
    "v_addc_co_u32 v61, vcc, 0, v61, vcc\n\t"                       \
    "s_waitcnt vmcnt(12)\n\t"                                       \
    "s_branch Ldn" TAG "_%=\n\t"                                    \
    "Lsk" TAG "_%=:\n\t"                                            \
    "s_waitcnt vmcnt(0)\n\t"                                        \
    "Ldn" TAG "_%=:\n\t"                                            \
    "s_add_i32 %[it], %[it], 1\n\t"

// ---------------------------------------------------------------------------
// Kernel 1: Bmat = expm(triu(A,1) - triu(A,1)^T) in fp64, write fp32 to ws.
// ---------------------------------------------------------------------------
__global__ void expm_kernel(const float* __restrict__ A, float* __restrict__ Bout) {
    __shared__ double S[H][H];
    __shared__ double P[H][H];
    __shared__ double E[H][H];
    const int tid = threadIdx.x;
    const int i = tid / H, j = tid % H;
    if (tid < H * H) {
        double a = 0.0;
        if (i < j) a = (double)A[i * H + j];
        else if (i > j) a = -(double)A[j * H + i];
        a *= (1.0 / 256.0);          // scale by 2^-8
        S[i][j] = a;
        P[i][j] = a;                 // S^1 / 1!
        E[i][j] = (i == j ? 1.0 : 0.0) + a;
    }
    __syncthreads();
    for (int k = 2; k <= 16; ++k) {
        double acc = 0.0;
        if (tid < H * H) {
            for (int m = 0; m < H; ++m) acc += P[i][m] * S[m][j];
            acc *= (1.0 / (double)k);
        }
        __syncthreads();
        if (tid < H * H) { P[i][j] = acc; E[i][j] += acc; }
        __syncthreads();
    }
    for (int rr = 0; rr < 8; ++rr) {
        double acc = 0.0;
        if (tid < H * H) {
            for (int m = 0; m < H; ++m) acc += E[i][m] * E[m][j];
        }
        __syncthreads();
        if (tid < H * H) E[i][j] = acc;
        __syncthreads();
    }
    if (tid < H * H) Bout[i * H + j] = (float)E[i][j];
}

// ---------------------------------------------------------------------------
// Kernel 2: full hand-asm recurrence loop.
// 16 lanes/batch (h[j] per lane, H 10->16, pads provably stay 0), 4 batches/
// wave, 2048 waves = 2/SIMD. 4 fixed x-buffers v64..v127 (8 steps each),
// depth-3 prefetch, counted s_waitcnt vmcnt(12). 23 VALU/step.
// ---------------------------------------------------------------------------
__global__ __launch_bounds__(64, 2)
void rnn_kernel(const float* __restrict__ x,
                const float* __restrict__ Bm,
                const float* __restrict__ Win,
                const float* __restrict__ bmod,
                const float* __restrict__ lW,
                const float* __restrict__ lb,
                float* __restrict__ out) {
    const int lane = threadIdx.x;
    const int j    = lane & 15;          // owned h component
    const int row  = lane >> 4;          // 0..3: batch within wave
    const int bb   = blockIdx.x * 4 + row;   // 8192 = 2048*4 exact

    // Rotation k delivers h[(j-k)&15]; Bv[k] = B[(j-k)&15][j] (0 on pads).
    float Bv[16];
#pragma unroll
    for (int k = 0; k < 16; ++k) {
        const int m = (j - k) & 15;
        Bv[k] = (j < H && m < H) ? Bm[m * H + j] : 0.f;
    }
    float w0j = 0.f, w1j = 0.f, bmj = 0.f;
    if (j < H) { w0j = Win[j * 2]; w1j = Win[j * 2 + 1]; bmj = bmod[j]; }

    float h = 0.f;
    int it = 0;
    const uint64_t addr = (uint64_t)(x + (size_t)bb * (T_LEN * 2));
    const unsigned alo = (unsigned)addr, ahi = (unsigned)(addr >> 32);

    asm volatile(
        // addr regs + prologue: stage bufs 0..2 (12 loads, 192 B)
        "v_mov_b32 v60, %[alo]\n\t"
        "v_mov_b32 v61, %[ahi]\n\t"
        "global_load_dwordx4 v[64:67],   v[60:61], off\n\t"
        "global_load_dwordx4 v[68:71],   v[60:61], off offset:16\n\t"
        "global_load_dwordx4 v[72:75],   v[60:61], off offset:32\n\t"
        "global_load_dwordx4 v[76:79],   v[60:61], off offset:48\n\t"
        "global_load_dwordx4 v[80:83],   v[60:61], off offset:64\n\t"
        "global_load_dwordx4 v[84:87],   v[60:61], off offset:80\n\t"
        "global_load_dwordx4 v[88:91],   v[60:61], off offset:96\n\t"
        "global_load_dwordx4 v[92:95],   v[60:61], off offset:112\n\t"
        "global_load_dwordx4 v[96:99],   v[60:61], off offset:128\n\t"
        "global_load_dwordx4 v[100:103], v[60:61], off offset:144\n\t"
        "global_load_dwordx4 v[104:107], v[60:61], off offset:160\n\t"
        "global_load_dwordx4 v[108:111], v[60:61], off offset:176\n\t"
        "v_add_co_u32 v60, vcc, 0xc0, v60\n\t"
        "v_addc_co_u32 v61, vcc, 0, v61, vcc\n\t"
        "Lmain_%=:\n\t"
        // sub0: reads buf0 (v64-79), issues buf3 (v112-127)
        SUBCTL("0", "v[112:115]", "v[116:119]", "v[120:123]", "v[124:127]")
        STEP(64, 65)  STEP(66, 67)  STEP(68, 69)  STEP(70, 71)
        STEP(72, 73)  STEP(74, 75)  STEP(76, 77)  STEP(78, 79)
        // sub1: reads buf1 (v80-95), issues buf0 (v64-79)
        SUBCTL("1", "v[64:67]", "v[68:71]", "v[72:75]", "v[76:79]")
        STEP(80, 81)  STEP(82, 83)  STEP(84, 85)  STEP(86, 87)
        STEP(88, 89)  STEP(90, 91)  STEP(92, 93)  STEP(94, 95)
        // sub2: reads buf2 (v96-111), issues buf1 (v80-95)
        SUBCTL("2", "v[80:83]", "v[84:87]", "v[88:91]", "v[92:95]")
        STEP(96, 97)  STEP(98, 99)  STEP(100, 101) STEP(102, 103)
        STEP(104, 105) STEP(106, 107) STEP(108, 109) STEP(110, 111)
        // sub3: reads buf3 (v112-127), issues buf2 (v96-111)
        SUBCTL("3", "v[96:99]", "v[100:103]", "v[104:107]", "v[108:111]")
        STEP(112, 113) STEP(114, 115) STEP(116, 117) STEP(118, 119)
        STEP(120, 121) STEP(122, 123) STEP(124, 125) STEP(126, 127)
        "s_cmp_lg_u32 %[it], 256\n\t"
        "s_cbranch_scc1 Lmain_%=\n\t"
        : [h] "+v"(h), [it] "+s"(it)
        : [alo] "v"(alo), [ahi] "v"(ahi),
          [w0] "v"(w0j), [w1] "v"(w1j), [bm] "v"(bmj),
          [mk] "s"(0x7fffffffu),
          [b0] "v"(Bv[0]),  [b1] "v"(Bv[1]),  [b2] "v"(Bv[2]),  [b3] "v"(Bv[3]),
          [b4] "v"(Bv[4]),  [b5] "v"(Bv[5]),  [b6] "v"(Bv[6]),  [b7] "v"(Bv[7]),
          [b8] "v"(Bv[8]),  [b9] "v"(Bv[9]),  [b10] "v"(Bv[10]), [b11] "v"(Bv[11]),
          [b12] "v"(Bv[12]), [b13] "v"(Bv[13]), [b14] "v"(Bv[14]), [b15] "v"(Bv[15])
        : "memory", "vcc", "scc",
          "v60", "v61", "v62", "v63", "v64", "v65", "v66", "v67", "v68", "v69",
          "v70", "v71", "v72", "v73", "v74", "v75", "v76", "v77", "v78", "v79",
          "v80", "v81", "v82", "v83", "v84", "v85", "v86", "v87", "v88", "v89",
          "v90", "v91", "v92", "v93", "v94", "v95", "v96", "v97", "v98", "v99",
          "v100", "v101", "v102", "v103", "v104", "v105", "v106", "v107",
          "v108", "v109", "v110", "v111", "v112", "v113", "v114", "v115",
          "v116", "v117", "v118", "v119", "v120", "v121", "v122", "v123",
          "v124", "v125", "v126", "v127");

    // epilogue: out[bb][j] = lb[j] + sum_m h[m] * lW[j][m] (cold; builtin DPP)
    float Lrot[16];
#pragma unroll
    for (int k = 0; k < 16; ++k) {
        const int m = (j - k) & 15;
        Lrot[k] = (j < H && m < H) ? lW[j * H + m] : 0.f;
    }
    float acc = (j < H) ? lb[j] : 0.f;
    acc = fmaf(h, Lrot[0], acc);
#define OUTK(K) { const float e_ = MOVROR(h, K); acc = fmaf(e_, Lrot[K], acc); }
    OUTK(1)  OUTK(2)  OUTK(3)  OUTK(4)  OUTK(5)
    OUTK(6)  OUTK(7)  OUTK(8)  OUTK(9)  OUTK(10)
    OUTK(11) OUTK(12) OUTK(13) OUTK(14) OUTK(15)
#undef OUTK
    if (j < H) out[(size_t)bb * H + j] = acc;
}

extern "C" void kernel_launch(void* const* d_in, const int* in_sizes, int n_in,
                              void* d_out, int out_size, void* d_ws, size_t ws_size,
                              hipStream_t stream) {
    const float* inputs = (const float*)d_in[0];  // [8192, 2048, 2]
    const float* A      = (const float*)d_in[1];  // [10, 10]
    const float* W_in   = (const float*)d_in[2];  // [10, 2]
    const float* b_mod  = (const float*)d_in[3];  // [10]
    const float* lin_W  = (const float*)d_in[4];  // [10, 10]
    const float* lin_b  = (const float*)d_in[5];  // [10]
    float* out = (float*)d_out;                   // [8192, 10]
    float* Bmat = (float*)d_ws;                   // 100 floats scratch

    expm_kernel<<<1, 128, 0, stream>>>(A, Bmat);
    rnn_kernel<<<BATCH / 4, 64, 0, stream>>>(inputs, Bmat, W_in, b_mod,
                                             lin_W, lin_b, out);
}